// Round 12
// baseline (5328.926 us; speedup 1.0000x reference)
//
#include <hip/hip_runtime.h>

#define TT 200
#define SS 1024
#define DD 512
#define VV 30
#define BB 64
#define BBDD (BB*DD)              // 32768

// ---- ws float offsets (r9 layout) ----
#define WS_H0   0                         // [2][64][512]
#define WS_GI   (2*BBDD)                  // [2][1536][64]
#define WS_H1A  (WS_GI + 2*1536*64)       // [200][64][512]
#define WS_CALL (WS_H1A + 200*BBDD)       // [200][64][512]

typedef __attribute__((ext_vector_type(4))) float f4;

__device__ __forceinline__ float dot4(f4 a, f4 b) {
  return a.x*b.x + a.y*b.y + a.z*b.z + a.w*b.w;
}
__device__ __forceinline__ float sigmoidf_(float x) { return 1.f/(1.f + __expf(-x)); }

__device__ __forceinline__ void gl_lds16(const void* g, void* l) {
  __builtin_amdgcn_global_load_lds(
      (const __attribute__((address_space(1))) unsigned int*)g,
      (__attribute__((address_space(3))) unsigned int*)l,
      16, 0, 0);
}

// async global [64][512] -> LDS [64][516] ; follow with __syncthreads()
__device__ __forceinline__ void stage64(const float* src, float* TILE, int wv, int lane) {
  #pragma unroll
  for (int rr = 0; rr < 8; ++rr) {
    const int row = wv*8 + rr;
    const float* g = src + (size_t)row*DD + lane*4;
    gl_lds16(g,       TILE + row*516);
    gl_lds16(g + 256, TILE + row*516 + 256);
  }
}

// wave-column GRU dots into LOCAL gate buffer GH[24][64]  (unroll 8: 24 loads in flight)
__device__ __forceinline__ void wave_dots(const float* TILE, const float* W, const float* bias,
                                          float* GH, int w_id, int wv, int lane) {
  const int c0 = wv*3, c1 = c0+1, c2 = c0+2;
  const int R0 = __builtin_amdgcn_readfirstlane(((c0>>3)<<9) + w_id*8 + (c0&7));
  const int R1 = __builtin_amdgcn_readfirstlane(((c1>>3)<<9) + w_id*8 + (c1&7));
  const int R2 = __builtin_amdgcn_readfirstlane(((c2>>3)<<9) + w_id*8 + (c2&7));
  const f4* w0 = (const f4*)(W + (size_t)R0*DD);
  const f4* w1 = (const f4*)(W + (size_t)R1*DD);
  const f4* w2 = (const f4*)(W + (size_t)R2*DD);
  const f4* hv4 = (const f4*)TILE + (size_t)lane*129;
  float a0=0.f, a1=0.f, a2=0.f;
  #pragma unroll 8
  for (int kq = 0; kq < 128; ++kq) {
    f4 h = hv4[kq];
    a0 += dot4(h, w0[kq]); a1 += dot4(h, w1[kq]); a2 += dot4(h, w2[kq]);
  }
  GH[c0*64 + lane] = a0 + bias[R0];
  GH[c1*64 + lane] = a1 + bias[R1];
  GH[c2*64 + lane] = a2 + bias[R2];
}

// wave-column dots writing GLOBAL gi buffer gi[(g*512+d)*64 + lane], bias included
__device__ __forceinline__ void wave_dots_g(const float* TILE, const float* W, const float* bias,
                                            float* gi, int w_id, int wv, int lane) {
  const int c0 = wv*3, c1 = c0+1, c2 = c0+2;
  const int R0 = __builtin_amdgcn_readfirstlane(((c0>>3)<<9) + w_id*8 + (c0&7));
  const int R1 = __builtin_amdgcn_readfirstlane(((c1>>3)<<9) + w_id*8 + (c1&7));
  const int R2 = __builtin_amdgcn_readfirstlane(((c2>>3)<<9) + w_id*8 + (c2&7));
  const f4* w0 = (const f4*)(W + (size_t)R0*DD);
  const f4* w1 = (const f4*)(W + (size_t)R1*DD);
  const f4* w2 = (const f4*)(W + (size_t)R2*DD);
  const f4* hv4 = (const f4*)TILE + (size_t)lane*129;
  float a0=0.f, a1=0.f, a2=0.f;
  #pragma unroll 8
  for (int kq = 0; kq < 128; ++kq) {
    f4 h = hv4[kq];
    a0 += dot4(h, w0[kq]); a1 += dot4(h, w1[kq]); a2 += dot4(h, w2[kq]);
  }
  gi[(size_t)R0*64 + lane] = a0 + bias[R0];
  gi[(size_t)R1*64 + lane] = a1 + bias[R1];
  gi[(size_t)R2*64 + lane] = a2 + bias[R2];
}

// ================= prologue 1: h0(0) =================
__launch_bounds__(512, 1)
__global__ void k_gru0(const float* __restrict__ h0prev, const int* __restrict__ targets,
                       const float* __restrict__ W_ih0, const float* __restrict__ W_hh0,
                       const float* __restrict__ b_ih0, const float* __restrict__ b_hh0,
                       float* __restrict__ h0out, int tokcol) {
  __shared__ float SM[34560];
  float* const TILE = SM;
  float* const GHX  = SM + 33024;
  const int tid = threadIdx.x, bid = blockIdx.x;
  const int lane = tid & 63, wv = tid >> 6;
  stage64(h0prev, TILE, wv, lane);
  __syncthreads();
  wave_dots(TILE, W_hh0, b_hh0, GHX, bid, wv, lane);
  __syncthreads();
  const int dl = tid >> 6, bb = tid & 63, d = bid*8 + dl;
  const int tok = targets[bb*TT + tokcol];
  float gir = W_ih0[(size_t)d*VV + tok]          + b_ih0[d];
  float giz = W_ih0[(size_t)(DD + d)*VV + tok]   + b_ih0[DD + d];
  float gin = W_ih0[(size_t)(2*DD + d)*VV + tok] + b_ih0[2*DD + d];
  float r_ = sigmoidf_(gir + GHX[(0*8 + dl)*64 + bb]);
  float z_ = sigmoidf_(giz + GHX[(1*8 + dl)*64 + bb]);
  float n_ = tanhf(gin + r_*GHX[(2*8 + dl)*64 + bb]);
  float h0old = TILE[bb*516 + d];
  h0out[(size_t)bb*DD + d] = (1.f - z_)*n_ + z_*h0old;
}

// ================= prologue 2: h0(1) [0..63] | GI1(0) [64..127] =================
__launch_bounds__(512, 1)
__global__ void k_pro1(const float* __restrict__ h0buf0, const int* __restrict__ targets,
                       const float* __restrict__ W_ih0, const float* __restrict__ W_hh0,
                       const float* __restrict__ b_ih0, const float* __restrict__ b_hh0,
                       const float* __restrict__ W_ih1, const float* __restrict__ b_ih1,
                       float* __restrict__ h0buf1, float* __restrict__ gibuf0) {
  __shared__ float SM[34560];
  float* const TILE = SM;
  float* const GHX  = SM + 33024;
  const int tid = threadIdx.x, bid = blockIdx.x;
  const int lane = tid & 63, wv = tid >> 6;
  stage64(h0buf0, TILE, wv, lane);
  __syncthreads();
  if (bid < 64) {
    wave_dots(TILE, W_hh0, b_hh0, GHX, bid, wv, lane);
    __syncthreads();
    const int dl = tid >> 6, bb = tid & 63, d = bid*8 + dl;
    const int tok = targets[bb*TT + 0];
    float gir = W_ih0[(size_t)d*VV + tok]          + b_ih0[d];
    float giz = W_ih0[(size_t)(DD + d)*VV + tok]   + b_ih0[DD + d];
    float gin = W_ih0[(size_t)(2*DD + d)*VV + tok] + b_ih0[2*DD + d];
    float r_ = sigmoidf_(gir + GHX[(0*8 + dl)*64 + bb]);
    float z_ = sigmoidf_(giz + GHX[(1*8 + dl)*64 + bb]);
    float n_ = tanhf(gin + r_*GHX[(2*8 + dl)*64 + bb]);
    float h0old = TILE[bb*516 + d];
    h0buf1[(size_t)bb*DD + d] = (1.f - z_)*n_ + z_*h0old;
  } else {
    wave_dots_g(TILE, W_ih1, b_ih1, gibuf0, bid - 64, wv, lane);
  }
}

// ======= chain: XCD-partitioned tasks (bid&7): {0,1,2}=h0/W_hh0, {3,4,5}=h1/W_hh1, {6,7}=GI/W_ih1
__launch_bounds__(512, 1)
__global__ void k_chain(const float* __restrict__ h0rd, float* __restrict__ h0wr,
                        const float* __restrict__ h1src, float* __restrict__ h1dst,
                        const float* __restrict__ gird, float* __restrict__ giwr,
                        const int* __restrict__ targets,
                        const float* __restrict__ W_ih0, const float* __restrict__ W_hh0,
                        const float* __restrict__ b_ih0, const float* __restrict__ b_hh0,
                        const float* __restrict__ W_hh1, const float* __restrict__ b_hh1,
                        const float* __restrict__ W_ih1, const float* __restrict__ b_ih1,
                        int t) {
  __shared__ float SM[34560];
  float* const TILE = SM;
  float* const GHX  = SM + 33024;
  const int tid = threadIdx.x, bid = blockIdx.x;
  const int lane = tid & 63, wv = tid >> 6;
  const int dl = tid >> 6, bb = tid & 63;
  const int xcd = bid & 7, brow = bid >> 3;

  if (xcd < 3) {
    const int k = brow*3 + xcd;
    if (k < 64 && t <= 197) {
      const int d = k*8 + dl;
      stage64(h0rd, TILE, wv, lane);
      __syncthreads();
      wave_dots(TILE, W_hh0, b_hh0, GHX, k, wv, lane);
      __syncthreads();
      const int tok = targets[bb*TT + (t + 1)];
      float gir = W_ih0[(size_t)d*VV + tok]          + b_ih0[d];
      float giz = W_ih0[(size_t)(DD + d)*VV + tok]   + b_ih0[DD + d];
      float gin = W_ih0[(size_t)(2*DD + d)*VV + tok] + b_ih0[2*DD + d];
      float r_ = sigmoidf_(gir + GHX[(0*8 + dl)*64 + bb]);
      float z_ = sigmoidf_(giz + GHX[(1*8 + dl)*64 + bb]);
      float n_ = tanhf(gin + r_*GHX[(2*8 + dl)*64 + bb]);
      float h0old = TILE[bb*516 + d];
      h0wr[(size_t)bb*DD + d] = (1.f - z_)*n_ + z_*h0old;
    }
  } else if (xcd < 6) {
    const int k = brow*3 + (xcd - 3);
    if (k < 64) {
      const int d = k*8 + dl;
      stage64(h1src, TILE, wv, lane);
      __syncthreads();
      wave_dots(TILE, W_hh1, b_hh1, GHX, k, wv, lane);
      float h1old = TILE[bb*516 + d];
      __syncthreads();
      float gir = gird[(size_t)(0*DD + d)*64 + bb];
      float giz = gird[(size_t)(1*DD + d)*64 + bb];
      float gin = gird[(size_t)(2*DD + d)*64 + bb];
      float r_ = sigmoidf_(gir + GHX[(0*8 + dl)*64 + bb]);
      float z_ = sigmoidf_(giz + GHX[(1*8 + dl)*64 + bb]);
      float n_ = tanhf(gin + r_*GHX[(2*8 + dl)*64 + bb]);
      h1dst[(size_t)bb*DD + d] = (1.f - z_)*n_ + z_*h1old;
    }
  } else {
    const int k = brow*2 + (xcd - 6);
    if (k < 64 && t <= 198) {
      stage64(h0rd, TILE, wv, lane);
      __syncthreads();
      wave_dots_g(TILE, W_ih1, b_ih1, giwr, k, wv, lane);
    }
  }
}

// ======= batched attention: 640-thread blocks, 2 blocks/CU, 8-row tiles =======
// block = (b = bid&63, tt = bid>>6): q-rows tt*20..tt*20+19, wave wv owns 2 rows.
// LDS: MT[2][8*516]=8256 | QL[20*516]=10320 | SCR[10][16]=160  -> 18736 floats (74.9 KB)
__launch_bounds__(640, 1)
__global__ void k_attn_all(const float* __restrict__ h1a, const float* __restrict__ mem,
                           float* __restrict__ call) {
  __shared__ float SM[18736];
  float* const QL  = SM + 8256;
  float* const SCR = SM + 8256 + 10320;
  const int tid = threadIdx.x, bid = blockIdx.x;
  const int lane = tid & 63, wv = tid >> 6;     // wv 0..9
  const int b = bid & 63, tt = bid >> 6;        // tt 0..9 (same-b blocks share an XCD's L2)
  const int g = lane >> 3, sub = lane & 7;

  // stage Q: wave wv stages its 2 rows
  #pragma unroll
  for (int rr = 0; rr < 2; ++rr) {
    const int row = wv*2 + rr;
    const float* src = h1a + ((size_t)(tt*20 + row)*BB + b)*DD + lane*4;
    gl_lds16(src,       QL + row*516);
    gl_lds16(src + 256, QL + row*516 + 256);
  }
  // stage mem tile 0 (threads 0..511: row = tid>>6)
  const float* msrc = mem + (size_t)b*SS*DD;
  if (tid < 512) {
    const int row = tid >> 6;
    const float* gsp = msrc + (size_t)row*DD + lane*4;
    gl_lds16(gsp,       SM + row*516);
    gl_lds16(gsp + 256, SM + row*516 + 256);
  }
  __syncthreads();

  f4 aa[2], ab[2]; float m[2], l[2];
  #pragma unroll
  for (int r = 0; r < 2; ++r) { aa[r] = (f4)0.f; ab[r] = (f4)0.f; m[r] = -3e38f; l[r] = 0.f; }

  int buf = 0;
  for (int tl = 0; tl < 128; ++tl) {
    if (tl + 1 < 128 && tid < 512) {
      float* nb = SM + (buf^1)*4128;
      const int row = tid >> 6;
      const float* gsp = msrc + ((size_t)(tl+1)*8 + row)*DD + lane*4;
      gl_lds16(gsp,       nb + row*516);
      gl_lds16(gsp + 256, nb + row*516 + 256);
    }
    const f4* mtf4 = (const f4*)(SM + buf*4128);   // 8 rows x 129 f4
    const f4* qlf4 = (const f4*)QL;

    // pass 1: lane (g,sub) -> 64-dim slice of score(q_r, s=g)
    float p0 = 0.f, p1 = 0.f;
    #pragma unroll 4
    for (int k = 0; k < 16; ++k) {
      const int idx = sub*16 + ((k + sub) & 15);   // rotated: per-phase conflict-free
      const f4 mv = mtf4[g*129 + idx];
      p0 += dot4(mv, qlf4[(wv*2 + 0)*129 + idx]);
      p1 += dot4(mv, qlf4[(wv*2 + 1)*129 + idx]);
    }
    p0 += __shfl_xor(p0, 1); p0 += __shfl_xor(p0, 2); p0 += __shfl_xor(p0, 4);
    p1 += __shfl_xor(p1, 1); p1 += __shfl_xor(p1, 2); p1 += __shfl_xor(p1, 4);
    if (sub == 0) { SCR[wv*16 + g] = p0; SCR[wv*16 + 8 + g] = p1; }
    // wave-internal LDS write->read: compiler inserts lgkmcnt (r11-proven pattern)

    // pass 2: online softmax + PV (lane <-> dims, stride-1)
    #pragma unroll
    for (int r = 0; r < 2; ++r) {
      float mx = SCR[wv*16 + r*8];
      #pragma unroll
      for (int s = 1; s < 8; ++s) mx = fmaxf(mx, SCR[wv*16 + r*8 + s]);
      const float mnew = fmaxf(m[r], mx);
      const float esc = __expf(m[r] - mnew);
      aa[r] *= esc; ab[r] *= esc; l[r] *= esc;
      m[r] = mnew;
    }
    #pragma unroll
    for (int s = 0; s < 8; ++s) {
      const f4 ma = mtf4[s*129 + lane];
      const f4 mb = mtf4[s*129 + 64 + lane];
      #pragma unroll
      for (int r = 0; r < 2; ++r) {
        const float w = __expf(SCR[wv*16 + r*8 + s] - m[r]);
        aa[r] += w*ma; ab[r] += w*mb; l[r] += w;
      }
    }
    __syncthreads();
    buf ^= 1;
  }

  #pragma unroll
  for (int r = 0; r < 2; ++r) {
    const float inv = 1.f / l[r];
    float* dst = call + ((size_t)(tt*20 + wv*2 + r)*BB + b)*DD;
    *(f4*)(dst + lane*4)       = aa[r]*inv;
    *(f4*)(dst + lane*4 + 256) = ab[r]*inv;
  }
}

// ======= output projection + logits =======
__launch_bounds__(512, 1)
__global__ void k_outproj(const float* __restrict__ call, const float* __restrict__ h1a,
                          const float* __restrict__ W_out, const float* __restrict__ W_tok,
                          const float* __restrict__ b_tok, float* __restrict__ out) {
  __shared__ float SM[4352 + 33024];       // XR[64][68] + AH[64][516]
  float* const XR = SM;
  float* const AH = SM + 4352;
  const int tid = threadIdx.x, bid = blockIdx.x;
  const int lane = tid & 63, wv = tid >> 6;
  const int rowbase = bid * 64;

  float acc[8][8];
  #pragma unroll
  for (int r = 0; r < 8; ++r)
    #pragma unroll
    for (int j = 0; j < 8; ++j) acc[r][j] = 0.f;

  for (int kc = 0; kc < 16; ++kc) {
    __syncthreads();
    {
      const int row = tid >> 3;
      const int kp  = (tid & 7) * 8;
      const int k   = kc*64 + kp;
      const size_t grow = (size_t)(rowbase + row) * DD;
      const float* src = (k < DD) ? (call + grow + k) : (h1a + grow + (k - DD));
      f4 v0 = *(const f4*)src;
      f4 v1 = *(const f4*)(src + 4);
      *(f4*)&XR[row*68 + kp]     = v0;
      *(f4*)&XR[row*68 + kp + 4] = v1;
    }
    __syncthreads();
    for (int k4 = 0; k4 < 16; ++k4) {
      f4 w4[8];
      #pragma unroll
      for (int j = 0; j < 8; ++j)
        w4[j] = *(const f4*)&W_out[(size_t)(lane*8 + j)*(2*DD) + kc*64 + k4*4];
      #pragma unroll
      for (int r = 0; r < 8; ++r) {
        const f4 x4 = *(const f4*)&XR[(wv*8 + r)*68 + k4*4];
        #pragma unroll
        for (int j = 0; j < 8; ++j) acc[r][j] += dot4(x4, w4[j]);
      }
    }
  }
  #pragma unroll
  for (int r = 0; r < 8; ++r) {
    f4 t0, t1;
    t0.x = tanhf(acc[r][0]); t0.y = tanhf(acc[r][1]); t0.z = tanhf(acc[r][2]); t0.w = tanhf(acc[r][3]);
    t1.x = tanhf(acc[r][4]); t1.y = tanhf(acc[r][5]); t1.z = tanhf(acc[r][6]); t1.w = tanhf(acc[r][7]);
    *(f4*)&AH[(wv*8 + r)*516 + lane*8]     = t0;
    *(f4*)&AH[(wv*8 + r)*516 + lane*8 + 4] = t1;
  }
  __syncthreads();
  const int v = tid & 31;
  const int rq = tid >> 5;
  if (v < VV) {
    for (int it = 0; it < 4; ++it) {
      const int row = rq + it*16;
      float s = 0.f;
      const f4* ar = (const f4*)&AH[row*516];
      const f4* wt = (const f4*)&W_tok[(size_t)v*DD];
      #pragma unroll 4
      for (int k4 = 0; k4 < 128; ++k4) s += dot4(ar[k4], wt[k4]);
      const int gr = rowbase + row;
      const int t = gr >> 6, b = gr & 63;
      out[((size_t)b*TT + t)*VV + v] = s + b_tok[v];
    }
  }
}

extern "C" void kernel_launch(void* const* d_in, const int* in_sizes, int n_in,
                              void* d_out, int out_size, void* d_ws, size_t ws_size,
                              hipStream_t stream) {
  const float* h_init = (const float*)d_in[0];
  const int*   targets= (const int*)d_in[1];
  const float* mem    = (const float*)d_in[2];
  const float* W_ih0  = (const float*)d_in[3];
  const float* W_hh0  = (const float*)d_in[4];
  const float* b_ih0  = (const float*)d_in[5];
  const float* b_hh0  = (const float*)d_in[6];
  const float* W_ih1  = (const float*)d_in[7];
  const float* W_hh1  = (const float*)d_in[8];
  const float* b_ih1  = (const float*)d_in[9];
  const float* b_hh1  = (const float*)d_in[10];
  const float* W_out  = (const float*)d_in[11];
  const float* W_tok  = (const float*)d_in[12];
  const float* b_tok  = (const float*)d_in[13];
  float* out = (float*)d_out;
  float* ws  = (float*)d_ws;

  float* h0b  = ws + WS_H0;
  float* gib  = ws + WS_GI;
  float* h1a  = ws + WS_H1A;
  float* call = ws + WS_CALL;

  // prologue: h0(0); then {h0(1) | GI1(0)}
  hipLaunchKernelGGL(k_gru0, dim3(64), dim3(512), 0, stream,
                     h_init, targets, W_ih0, W_hh0, b_ih0, b_hh0, h0b, 0);
  hipLaunchKernelGGL(k_pro1, dim3(128), dim3(512), 0, stream,
                     h0b, targets, W_ih0, W_hh0, b_ih0, b_hh0,
                     W_ih1, b_ih1, h0b + BBDD, gib);

  // chain: L(t) -> h1(t), h0(t+2), GI1(t+1)  (XCD-partitioned, grid 256)
  for (int t = 0; t < TT; ++t) {
    const float* h0rd = h0b + (size_t)((t + 1) & 1)*BBDD;
    float*       h0wr = h0b + (size_t)(t & 1)*BBDD;
    const float* h1src= (t == 0) ? (h_init + BBDD) : (h1a + (size_t)(t - 1)*BBDD);
    float*       h1dst= h1a + (size_t)t*BBDD;
    const float* gird = gib + (size_t)(t & 1)*(1536*64);
    float*       giwr = gib + (size_t)((t + 1) & 1)*(1536*64);
    hipLaunchKernelGGL(k_chain, dim3(256), dim3(512), 0, stream,
                       h0rd, h0wr, h1src, h1dst, gird, giwr, targets,
                       W_ih0, W_hh0, b_ih0, b_hh0, W_hh1, b_hh1, W_ih1, b_ih1, t);
  }

  // batched attention over all 200 steps (640 blocks, 2 blocks/CU)
  hipLaunchKernelGGL(k_attn_all, dim3(640), dim3(640), 0, stream, h1a, mem, call);

  // output projection + logits
  hipLaunchKernelGGL(k_outproj, dim3(200), dim3(512), 0, stream,
                     call, h1a, W_out, W_tok, b_tok, out);
}

// Round 13
// 4570.771 us; speedup vs baseline: 1.1659x; 1.1659x over previous
//
#include <hip/hip_runtime.h>

#define TT 200
#define SS 1024
#define DD 512
#define VV 30
#define BB 64
#define BBDD (BB*DD)              // 32768

// ---- ws float offsets (r9 layout) ----
#define WS_H0   0                         // [2][64][512]
#define WS_GI   (2*BBDD)                  // [2][1536][64]
#define WS_H1A  (WS_GI + 2*1536*64)       // [200][64][512]
#define WS_CALL (WS_H1A + 200*BBDD)       // [200][64][512]

typedef __attribute__((ext_vector_type(4))) float f4;

__device__ __forceinline__ float dot4(f4 a, f4 b) {
  return a.x*b.x + a.y*b.y + a.z*b.z + a.w*b.w;
}
__device__ __forceinline__ float sigmoidf_(float x) { return 1.f/(1.f + __expf(-x)); }

__device__ __forceinline__ void gl_lds16(const void* g, void* l) {
  __builtin_amdgcn_global_load_lds(
      (const __attribute__((address_space(1))) unsigned int*)g,
      (__attribute__((address_space(3))) unsigned int*)l,
      16, 0, 0);
}

// async global [64][512] -> LDS [64][516] ; follow with __syncthreads()
__device__ __forceinline__ void stage64(const float* src, float* TILE, int wv, int lane) {
  #pragma unroll
  for (int rr = 0; rr < 8; ++rr) {
    const int row = wv*8 + rr;
    const float* g = src + (size_t)row*DD + lane*4;
    gl_lds16(g,       TILE + row*516);
    gl_lds16(g + 256, TILE + row*516 + 256);
  }
}

// wave-column GRU dots into LOCAL gate buffer GH[24][64]
__device__ __forceinline__ void wave_dots(const float* TILE, const float* W, const float* bias,
                                          float* GH, int w_id, int wv, int lane) {
  const int c0 = wv*3, c1 = c0+1, c2 = c0+2;
  const int R0 = __builtin_amdgcn_readfirstlane(((c0>>3)<<9) + w_id*8 + (c0&7));
  const int R1 = __builtin_amdgcn_readfirstlane(((c1>>3)<<9) + w_id*8 + (c1&7));
  const int R2 = __builtin_amdgcn_readfirstlane(((c2>>3)<<9) + w_id*8 + (c2&7));
  const f4* w0 = (const f4*)(W + (size_t)R0*DD);
  const f4* w1 = (const f4*)(W + (size_t)R1*DD);
  const f4* w2 = (const f4*)(W + (size_t)R2*DD);
  const f4* hv4 = (const f4*)TILE + (size_t)lane*129;
  float a0=0.f, a1=0.f, a2=0.f;
  #pragma unroll 4
  for (int kq = 0; kq < 128; ++kq) {
    f4 h = hv4[kq];
    a0 += dot4(h, w0[kq]); a1 += dot4(h, w1[kq]); a2 += dot4(h, w2[kq]);
  }
  GH[c0*64 + lane] = a0 + bias[R0];
  GH[c1*64 + lane] = a1 + bias[R1];
  GH[c2*64 + lane] = a2 + bias[R2];
}

// wave-column dots writing GLOBAL gi buffer gi[(g*512+d)*64 + lane], bias included
__device__ __forceinline__ void wave_dots_g(const float* TILE, const float* W, const float* bias,
                                            float* gi, int w_id, int wv, int lane) {
  const int c0 = wv*3, c1 = c0+1, c2 = c0+2;
  const int R0 = __builtin_amdgcn_readfirstlane(((c0>>3)<<9) + w_id*8 + (c0&7));
  const int R1 = __builtin_amdgcn_readfirstlane(((c1>>3)<<9) + w_id*8 + (c1&7));
  const int R2 = __builtin_amdgcn_readfirstlane(((c2>>3)<<9) + w_id*8 + (c2&7));
  const f4* w0 = (const f4*)(W + (size_t)R0*DD);
  const f4* w1 = (const f4*)(W + (size_t)R1*DD);
  const f4* w2 = (const f4*)(W + (size_t)R2*DD);
  const f4* hv4 = (const f4*)TILE + (size_t)lane*129;
  float a0=0.f, a1=0.f, a2=0.f;
  #pragma unroll 4
  for (int kq = 0; kq < 128; ++kq) {
    f4 h = hv4[kq];
    a0 += dot4(h, w0[kq]); a1 += dot4(h, w1[kq]); a2 += dot4(h, w2[kq]);
  }
  gi[(size_t)R0*64 + lane] = a0 + bias[R0];
  gi[(size_t)R1*64 + lane] = a1 + bias[R1];
  gi[(size_t)R2*64 + lane] = a2 + bias[R2];
}

// ================= prologue 1: h0(0) =================
__launch_bounds__(512, 1)
__global__ void k_gru0(const float* __restrict__ h0prev, const int* __restrict__ targets,
                       const float* __restrict__ W_ih0, const float* __restrict__ W_hh0,
                       const float* __restrict__ b_ih0, const float* __restrict__ b_hh0,
                       float* __restrict__ h0out, int tokcol) {
  __shared__ float SM[34560];
  float* const TILE = SM;
  float* const GHX  = SM + 33024;
  const int tid = threadIdx.x, bid = blockIdx.x;
  const int lane = tid & 63, wv = tid >> 6;
  stage64(h0prev, TILE, wv, lane);
  __syncthreads();
  wave_dots(TILE, W_hh0, b_hh0, GHX, bid, wv, lane);
  __syncthreads();
  const int dl = tid >> 6, bb = tid & 63, d = bid*8 + dl;
  const int tok = targets[bb*TT + tokcol];
  float gir = W_ih0[(size_t)d*VV + tok]          + b_ih0[d];
  float giz = W_ih0[(size_t)(DD + d)*VV + tok]   + b_ih0[DD + d];
  float gin = W_ih0[(size_t)(2*DD + d)*VV + tok] + b_ih0[2*DD + d];
  float r_ = sigmoidf_(gir + GHX[(0*8 + dl)*64 + bb]);
  float z_ = sigmoidf_(giz + GHX[(1*8 + dl)*64 + bb]);
  float n_ = tanhf(gin + r_*GHX[(2*8 + dl)*64 + bb]);
  float h0old = TILE[bb*516 + d];
  h0out[(size_t)bb*DD + d] = (1.f - z_)*n_ + z_*h0old;
}

// ================= prologue 2: h0(1) [0..63] | GI1(0) [64..127] =================
__launch_bounds__(512, 1)
__global__ void k_pro1(const float* __restrict__ h0buf0, const int* __restrict__ targets,
                       const float* __restrict__ W_ih0, const float* __restrict__ W_hh0,
                       const float* __restrict__ b_ih0, const float* __restrict__ b_hh0,
                       const float* __restrict__ W_ih1, const float* __restrict__ b_ih1,
                       float* __restrict__ h0buf1, float* __restrict__ gibuf0) {
  __shared__ float SM[34560];
  float* const TILE = SM;
  float* const GHX  = SM + 33024;
  const int tid = threadIdx.x, bid = blockIdx.x;
  const int lane = tid & 63, wv = tid >> 6;
  stage64(h0buf0, TILE, wv, lane);
  __syncthreads();
  if (bid < 64) {
    wave_dots(TILE, W_hh0, b_hh0, GHX, bid, wv, lane);
    __syncthreads();
    const int dl = tid >> 6, bb = tid & 63, d = bid*8 + dl;
    const int tok = targets[bb*TT + 0];
    float gir = W_ih0[(size_t)d*VV + tok]          + b_ih0[d];
    float giz = W_ih0[(size_t)(DD + d)*VV + tok]   + b_ih0[DD + d];
    float gin = W_ih0[(size_t)(2*DD + d)*VV + tok] + b_ih0[2*DD + d];
    float r_ = sigmoidf_(gir + GHX[(0*8 + dl)*64 + bb]);
    float z_ = sigmoidf_(giz + GHX[(1*8 + dl)*64 + bb]);
    float n_ = tanhf(gin + r_*GHX[(2*8 + dl)*64 + bb]);
    float h0old = TILE[bb*516 + d];
    h0buf1[(size_t)bb*DD + d] = (1.f - z_)*n_ + z_*h0old;
  } else {
    wave_dots_g(TILE, W_ih1, b_ih1, gibuf0, bid - 64, wv, lane);
  }
}

// ======= chain: h0(t+2) [0..63] | h1(t) [64..127] | GI1(t+1) [128..191] =======
__launch_bounds__(512, 1)
__global__ void k_chain(const float* __restrict__ h0rd, float* __restrict__ h0wr,
                        const float* __restrict__ h1src, float* __restrict__ h1dst,
                        const float* __restrict__ gird, float* __restrict__ giwr,
                        const int* __restrict__ targets,
                        const float* __restrict__ W_ih0, const float* __restrict__ W_hh0,
                        const float* __restrict__ b_ih0, const float* __restrict__ b_hh0,
                        const float* __restrict__ W_hh1, const float* __restrict__ b_hh1,
                        const float* __restrict__ W_ih1, const float* __restrict__ b_ih1,
                        int t) {
  __shared__ float SM[34560];
  float* const TILE = SM;
  float* const GHX  = SM + 33024;
  const int tid = threadIdx.x, bid = blockIdx.x;
  const int lane = tid & 63, wv = tid >> 6;
  const int dl = tid >> 6, bb = tid & 63;

  if (bid < 64) {
    if (t <= 197) {
      const int d = bid*8 + dl;
      stage64(h0rd, TILE, wv, lane);
      __syncthreads();
      wave_dots(TILE, W_hh0, b_hh0, GHX, bid, wv, lane);
      __syncthreads();
      const int tok = targets[bb*TT + (t + 1)];
      float gir = W_ih0[(size_t)d*VV + tok]          + b_ih0[d];
      float giz = W_ih0[(size_t)(DD + d)*VV + tok]   + b_ih0[DD + d];
      float gin = W_ih0[(size_t)(2*DD + d)*VV + tok] + b_ih0[2*DD + d];
      float r_ = sigmoidf_(gir + GHX[(0*8 + dl)*64 + bb]);
      float z_ = sigmoidf_(giz + GHX[(1*8 + dl)*64 + bb]);
      float n_ = tanhf(gin + r_*GHX[(2*8 + dl)*64 + bb]);
      float h0old = TILE[bb*516 + d];
      h0wr[(size_t)bb*DD + d] = (1.f - z_)*n_ + z_*h0old;
    }
  } else if (bid < 128) {
    const int w_id = bid - 64;
    const int d = w_id*8 + dl;
    stage64(h1src, TILE, wv, lane);
    __syncthreads();
    wave_dots(TILE, W_hh1, b_hh1, GHX, w_id, wv, lane);
    float h1old = TILE[bb*516 + d];
    __syncthreads();
    float gir = gird[(size_t)(0*DD + d)*64 + bb];
    float giz = gird[(size_t)(1*DD + d)*64 + bb];
    float gin = gird[(size_t)(2*DD + d)*64 + bb];
    float r_ = sigmoidf_(gir + GHX[(0*8 + dl)*64 + bb]);
    float z_ = sigmoidf_(giz + GHX[(1*8 + dl)*64 + bb]);
    float n_ = tanhf(gin + r_*GHX[(2*8 + dl)*64 + bb]);
    h1dst[(size_t)bb*DD + d] = (1.f - z_)*n_ + z_*h1old;
  } else {
    if (t <= 198) {
      stage64(h0rd, TILE, wv, lane);
      __syncthreads();
      wave_dots_g(TILE, W_ih1, b_ih1, giwr, bid - 128, wv, lane);
    }
  }
}

// ======= batched attention: r11 structure + per-wave exp dedup =======
// block = (b, 40-row t-chunk); 16-row mem tiles double-buffered.
// LDS: MT[2][16*516]=16512 | QL[40*516]=20640 | SCR[8][80]=640 | WB[8][80]=640 -> 38432 floats (153.7KB)
__launch_bounds__(512, 1)
__global__ void k_attn_all(const float* __restrict__ h1a, const float* __restrict__ mem,
                           float* __restrict__ call) {
  __shared__ float SM[38432];
  float* const QL  = SM + 16512;
  float* const SCR = SM + 37152;
  float* const WB  = SM + 37792;
  const int tid = threadIdx.x, bid = blockIdx.x;
  const int lane = tid & 63, wv = tid >> 6;
  const int b = bid / 5, tt = bid % 5;
  const int g = lane >> 2, sub = lane & 3;

  // stage Q rows (each wave stages its own 5 q-rows)
  #pragma unroll
  for (int rr = 0; rr < 5; ++rr) {
    const int row = wv*5 + rr;
    const float* src = h1a + ((size_t)(tt*40 + row)*BB + b)*DD + lane*4;
    gl_lds16(src,       QL + row*516);
    gl_lds16(src + 256, QL + row*516 + 256);
  }
  // stage mem tile 0
  const float* msrc = mem + (size_t)b*SS*DD;
  #pragma unroll
  for (int rr = 0; rr < 2; ++rr) {
    const int row = wv*2 + rr;
    const float* gsp = msrc + (size_t)row*DD + lane*4;
    gl_lds16(gsp,       SM + row*516);
    gl_lds16(gsp + 256, SM + row*516 + 256);
  }
  __syncthreads();

  f4 aa[5], ab[5]; float m[5], l[5];
  #pragma unroll
  for (int r = 0; r < 5; ++r) { aa[r] = (f4)0.f; ab[r] = (f4)0.f; m[r] = -3e38f; l[r] = 0.f; }

  int buf = 0;
  for (int tl = 0; tl < 64; ++tl) {
    if (tl + 1 < 64) {
      float* nb = SM + (buf^1)*8256;
      #pragma unroll
      for (int rr = 0; rr < 2; ++rr) {
        const int row = wv*2 + rr;
        const float* gsp = msrc + (size_t)(tl+1)*16*DD + (size_t)row*DD + lane*4;
        gl_lds16(gsp,       nb + row*516);
        gl_lds16(gsp + 256, nb + row*516 + 256);
      }
    }
    const f4* mtf4 = (const f4*)(SM + buf*8256);   // row stride 129 f4
    const f4* qlf4 = (const f4*)QL;

    // pass 1: lane (g,sub) computes 128-dim partial of score(q_r, s=g)
    float p[5] = {0.f, 0.f, 0.f, 0.f, 0.f};
    #pragma unroll 4
    for (int k = 0; k < 32; ++k) {
      const int idx = sub*32 + ((k + sub) & 31);   // sub-rotated: conflict-free
      const f4 mv = mtf4[g*129 + idx];
      #pragma unroll
      for (int r = 0; r < 5; ++r)
        p[r] += dot4(mv, qlf4[(wv*5 + r)*129 + idx]);
    }
    #pragma unroll
    for (int r = 0; r < 5; ++r) {
      p[r] += __shfl_xor(p[r], 1);
      p[r] += __shfl_xor(p[r], 2);
    }
    if (sub == 0) {
      #pragma unroll
      for (int r = 0; r < 5; ++r) SCR[wv*80 + r*16 + g] = p[r];
    }
    // wave-internal LDS write->read; compiler inserts lgkmcnt

    // pass 2a: per-row running max + rescale (values identical across lanes)
    #pragma unroll
    for (int r = 0; r < 5; ++r) {
      float mx = SCR[wv*80 + r*16];
      #pragma unroll
      for (int s = 1; s < 16; ++s) mx = fmaxf(mx, SCR[wv*80 + r*16 + s]);
      const float mnew = fmaxf(m[r], mx);
      const float esc = __expf(m[r] - mnew);
      aa[r] *= esc; ab[r] *= esc; l[r] *= esc;
      m[r] = mnew;
    }
    // pass 2b: exp dedup — each lane computes 1-2 of the wave's 80 w values
    {
      const float mr = (lane < 16) ? m[0] : (lane < 32) ? m[1] : (lane < 48) ? m[2] : m[3];
      WB[wv*80 + lane] = __expf(SCR[wv*80 + lane] - mr);
      if (lane < 16)
        WB[wv*80 + 64 + lane] = __expf(SCR[wv*80 + 64 + lane] - m[4]);
    }
    // pass 2c: PV accumulate (w read as LDS broadcast)
    #pragma unroll
    for (int s = 0; s < 16; ++s) {
      const f4 ma = mtf4[s*129 + lane];
      const f4 mb = mtf4[s*129 + lane + 64];
      #pragma unroll
      for (int r = 0; r < 5; ++r) {
        const float w = WB[wv*80 + r*16 + s];
        aa[r] += w*ma; ab[r] += w*mb; l[r] += w;
      }
    }
    __syncthreads();
    buf ^= 1;
  }

  #pragma unroll
  for (int r = 0; r < 5; ++r) {
    const float inv = 1.f / l[r];
    float* dst = call + ((size_t)(tt*40 + wv*5 + r)*BB + b)*DD;
    *(f4*)(dst + lane*4)       = aa[r]*inv;
    *(f4*)(dst + lane*4 + 256) = ab[r]*inv;
  }
}

// ======= output projection + logits =======
__launch_bounds__(512, 1)
__global__ void k_outproj(const float* __restrict__ call, const float* __restrict__ h1a,
                          const float* __restrict__ W_out, const float* __restrict__ W_tok,
                          const float* __restrict__ b_tok, float* __restrict__ out) {
  __shared__ float SM[4352 + 33024];       // XR[64][68] + AH[64][516]
  float* const XR = SM;
  float* const AH = SM + 4352;
  const int tid = threadIdx.x, bid = blockIdx.x;
  const int lane = tid & 63, wv = tid >> 6;
  const int rowbase = bid * 64;

  float acc[8][8];
  #pragma unroll
  for (int r = 0; r < 8; ++r)
    #pragma unroll
    for (int j = 0; j < 8; ++j) acc[r][j] = 0.f;

  for (int kc = 0; kc < 16; ++kc) {
    __syncthreads();
    {
      const int row = tid >> 3;
      const int kp  = (tid & 7) * 8;
      const int k   = kc*64 + kp;
      const size_t grow = (size_t)(rowbase + row) * DD;
      const float* src = (k < DD) ? (call + grow + k) : (h1a + grow + (k - DD));
      f4 v0 = *(const f4*)src;
      f4 v1 = *(const f4*)(src + 4);
      *(f4*)&XR[row*68 + kp]     = v0;
      *(f4*)&XR[row*68 + kp + 4] = v1;
    }
    __syncthreads();
    for (int k4 = 0; k4 < 16; ++k4) {
      f4 w4[8];
      #pragma unroll
      for (int j = 0; j < 8; ++j)
        w4[j] = *(const f4*)&W_out[(size_t)(lane*8 + j)*(2*DD) + kc*64 + k4*4];
      #pragma unroll
      for (int r = 0; r < 8; ++r) {
        const f4 x4 = *(const f4*)&XR[(wv*8 + r)*68 + k4*4];
        #pragma unroll
        for (int j = 0; j < 8; ++j) acc[r][j] += dot4(x4, w4[j]);
      }
    }
  }
  #pragma unroll
  for (int r = 0; r < 8; ++r) {
    f4 t0, t1;
    t0.x = tanhf(acc[r][0]); t0.y = tanhf(acc[r][1]); t0.z = tanhf(acc[r][2]); t0.w = tanhf(acc[r][3]);
    t1.x = tanhf(acc[r][4]); t1.y = tanhf(acc[r][5]); t1.z = tanhf(acc[r][6]); t1.w = tanhf(acc[r][7]);
    *(f4*)&AH[(wv*8 + r)*516 + lane*8]     = t0;
    *(f4*)&AH[(wv*8 + r)*516 + lane*8 + 4] = t1;
  }
  __syncthreads();
  const int v = tid & 31;
  const int rq = tid >> 5;
  if (v < VV) {
    for (int it = 0; it < 4; ++it) {
      const int row = rq + it*16;
      float s = 0.f;
      const f4* ar = (const f4*)&AH[row*516];
      const f4* wt = (const f4*)&W_tok[(size_t)v*DD];
      #pragma unroll 4
      for (int k4 = 0; k4 < 128; ++k4) s += dot4(ar[k4], wt[k4]);
      const int gr = rowbase + row;
      const int t = gr >> 6, b = gr & 63;
      out[((size_t)b*TT + t)*VV + v] = s + b_tok[v];
    }
  }
}

extern "C" void kernel_launch(void* const* d_in, const int* in_sizes, int n_in,
                              void* d_out, int out_size, void* d_ws, size_t ws_size,
                              hipStream_t stream) {
  const float* h_init = (const float*)d_in[0];
  const int*   targets= (const int*)d_in[1];
  const float* mem    = (const float*)d_in[2];
  const float* W_ih0  = (const float*)d_in[3];
  const float* W_hh0  = (const float*)d_in[4];
  const float* b_ih0  = (const float*)d_in[5];
  const float* b_hh0  = (const float*)d_in[6];
  const float* W_ih1  = (const float*)d_in[7];
  const float* W_hh1  = (const float*)d_in[8];
  const float* b_ih1  = (const float*)d_in[9];
  const float* b_hh1  = (const float*)d_in[10];
  const float* W_out  = (const float*)d_in[11];
  const float* W_tok  = (const float*)d_in[12];
  const float* b_tok  = (const float*)d_in[13];
  float* out = (float*)d_out;
  float* ws  = (float*)d_ws;

  float* h0b  = ws + WS_H0;
  float* gib  = ws + WS_GI;
  float* h1a  = ws + WS_H1A;
  float* call = ws + WS_CALL;

  // prologue: h0(0); then {h0(1) | GI1(0)}
  hipLaunchKernelGGL(k_gru0, dim3(64), dim3(512), 0, stream,
                     h_init, targets, W_ih0, W_hh0, b_ih0, b_hh0, h0b, 0);
  hipLaunchKernelGGL(k_pro1, dim3(128), dim3(512), 0, stream,
                     h0b, targets, W_ih0, W_hh0, b_ih0, b_hh0,
                     W_ih1, b_ih1, h0b + BBDD, gib);

  // chain: L(t) -> h1(t), h0(t+2), GI1(t+1)  (per-step launches; proven)
  for (int t = 0; t < TT; ++t) {
    const float* h0rd = h0b + (size_t)((t + 1) & 1)*BBDD;
    float*       h0wr = h0b + (size_t)(t & 1)*BBDD;
    const float* h1src= (t == 0) ? (h_init + BBDD) : (h1a + (size_t)(t - 1)*BBDD);
    float*       h1dst= h1a + (size_t)t*BBDD;
    const float* gird = gib + (size_t)(t & 1)*(1536*64);
    float*       giwr = gib + (size_t)((t + 1) & 1)*(1536*64);
    hipLaunchKernelGGL(k_chain, dim3(192), dim3(512), 0, stream,
                       h0rd, h0wr, h1src, h1dst, gird, giwr, targets,
                       W_ih0, W_hh0, b_ih0, b_hh0, W_hh1, b_hh1, W_ih1, b_ih1, t);
  }

  // batched attention over all 200 steps
  hipLaunchKernelGGL(k_attn_all, dim3(320), dim3(512), 0, stream, h1a, mem, call);

  // output projection + logits
  hipLaunchKernelGGL(k_outproj, dim3(200), dim3(512), 0, stream,
                     call, h1a, W_out, W_tok, b_tok, out);
}